// Round 1
// baseline (5748.691 us; speedup 1.0000x reference)
//
#include <hip/hip_runtime.h>
#include <math.h>

#define NB 16
#define NC 256
#define NN 4096
#define ND 32

// ---------------------------------------------------------------------------
// Kernel 1: fused q/k/v 1x1-conv projections.
// x: [B][C][N].  Outputs:
//   Pq[b][n][d] = sum_c Wq[d,c] x[b,c,n]   (= q projection, used as K' keys)
//   Pk[b][n][d] = sum_c Wk[d,c] x[b,c,n]   (= k projection, used as Q' queries)
//   Vt[b][n][e] = sum_c Wv[e,c] x[b,c,n]   (= v^T, used as V')
// One block = one batch b and a 32-column n-tile. 256 threads.
// ---------------------------------------------------------------------------
__global__ __launch_bounds__(256) void proj_kernel(
    const float* __restrict__ x, const float* __restrict__ Wq,
    const float* __restrict__ Wk, const float* __restrict__ Wv,
    float* __restrict__ Pq, float* __restrict__ Pk, float* __restrict__ Vt)
{
    __shared__ float xs[NC][33];               // x tile [c][n_local], padded
    const int b  = blockIdx.x >> 7;            // / 128 tiles
    const int n0 = (blockIdx.x & 127) << 5;    // * 32
    const int tid = threadIdx.x;
    const float* xb = x + (size_t)b * NC * NN;

    // coalesced load of x[:, n0:n0+32]
    for (int i = tid; i < NC * 32; i += 256) {
        int c = i >> 5, n = i & 31;
        xs[c][n] = xb[(size_t)c * NN + n0 + n];
    }
    __syncthreads();

    const int n = tid & 31;
    const int g = tid >> 5;                    // 0..7

    // ---- q/k phase: this thread computes d = g*4 + j, j=0..3
    float aq[4] = {0.f,0.f,0.f,0.f}, ak[4] = {0.f,0.f,0.f,0.f};
    for (int c = 0; c < NC; ++c) {
        float xv = xs[c][n];
        #pragma unroll
        for (int j = 0; j < 4; ++j) {
            aq[j] += Wq[(g*4+j)*NC + c] * xv;
            ak[j] += Wk[(g*4+j)*NC + c] * xv;
        }
    }
    {
        size_t row = ((size_t)b * NN + n0 + n) * ND + g*4;
        *(float4*)(Pq + row) = make_float4(aq[0], aq[1], aq[2], aq[3]);
        *(float4*)(Pk + row) = make_float4(ak[0], ak[1], ak[2], ak[3]);
    }

    // ---- v phase: this thread computes e = g*32 + j, j=0..31
    float av[32];
    #pragma unroll
    for (int j = 0; j < 32; ++j) av[j] = 0.f;
    const float4* Wv4 = (const float4*)Wv;
    for (int c4 = 0; c4 < NC/4; ++c4) {
        float x0 = xs[c4*4+0][n], x1 = xs[c4*4+1][n];
        float x2 = xs[c4*4+2][n], x3 = xs[c4*4+3][n];
        #pragma unroll
        for (int j = 0; j < 32; ++j) {
            float4 w = Wv4[(size_t)(g*32+j)*(NC/4) + c4];
            av[j] += w.x*x0 + w.y*x1 + w.z*x2 + w.w*x3;
        }
    }
    float* vrow = Vt + ((size_t)b * NN + n0 + n) * NC + g*32;
    #pragma unroll
    for (int j4 = 0; j4 < 8; ++j4)
        *(float4*)(vrow + j4*4) = make_float4(av[j4*4], av[j4*4+1], av[j4*4+2], av[j4*4+3]);
}

// ---------------------------------------------------------------------------
// Kernel 2: flash attention over n (softmax axis) for each output column m.
//   s[m][n] = sum_d Pk[b][m][d] * Pq[b][n][d]
//   w(m,n)  = softmax over n
//   O[m][e] = sum_n w(m,n) Vt[b][n][e]
//   y[b,e,m] = gamma*O[m][e] + x[b,e,m]
// Block: BM=64 rows m, 256 threads: thread = (m = tid&63, g = tid>>6),
// owns O[m][g*64 .. g*64+63]. Iterates BN=32 key tiles with online softmax.
// ---------------------------------------------------------------------------
__global__ __launch_bounds__(256) void attn_kernel(
    const float* __restrict__ Pq,   // keys  K' [B][N][D]
    const float* __restrict__ Pk,   // query Q' [B][N][D]
    const float* __restrict__ Vt,   // V' [B][N][C]
    const float* __restrict__ x,
    const float* __restrict__ gamma_p,
    float* __restrict__ y)
{
    __shared__ float kt[32][36];        // K' tile [n][d], pad 36 (16B-aligned rows)
    __shared__ float s_lds[64][33];     // scores [m][n]
    __shared__ float v_lds[32][NC];     // V' tile [n][e]

    const int b  = blockIdx.x >> 6;     // / 64 m-blocks
    const int m0 = (blockIdx.x & 63) << 6;
    const int tid = threadIdx.x;
    const int m = tid & 63;
    const int g = tid >> 6;             // 0..3

    // query row (fixed for whole block) into registers, coalesced
    float qreg[ND];
    {
        const float4* qrow = (const float4*)(Pk + ((size_t)b*NN + m0 + m) * ND);
        #pragma unroll
        for (int d4 = 0; d4 < ND/4; ++d4) {
            float4 q4 = qrow[d4];
            qreg[d4*4+0] = q4.x; qreg[d4*4+1] = q4.y;
            qreg[d4*4+2] = q4.z; qreg[d4*4+3] = q4.w;
        }
    }

    float acc[64];
    #pragma unroll
    for (int j = 0; j < 64; ++j) acc[j] = 0.f;
    float mx = -INFINITY, l = 0.f;

    for (int t = 0; t < NN/32; ++t) {
        const int n0 = t * 32;
        // load K' tile
        for (int i = tid; i < 32*ND; i += 256) {
            int nn = i >> 5, d = i & 31;
            kt[nn][d] = Pq[((size_t)b*NN + n0 + nn)*ND + d];
        }
        // load V' tile (float4, coalesced)
        {
            const float4* vsrc = (const float4*)(Vt + ((size_t)b*NN + n0)*NC);
            float4* vdst = (float4*)v_lds;
            for (int i = tid; i < 32*NC/4; i += 256) vdst[i] = vsrc[i];
        }
        __syncthreads();

        // scores: thread computes s[m][nn] for nn = g*8..g*8+7
        #pragma unroll
        for (int jj = 0; jj < 8; ++jj) {
            int nn = g*8 + jj;
            const float4* krow = (const float4*)&kt[nn][0];
            float s = 0.f;
            #pragma unroll
            for (int d4 = 0; d4 < ND/4; ++d4) {
                float4 k4 = krow[d4];
                s += k4.x*qreg[d4*4] + k4.y*qreg[d4*4+1]
                   + k4.z*qreg[d4*4+2] + k4.w*qreg[d4*4+3];
            }
            s_lds[m][nn] = s;
        }
        __syncthreads();

        // online softmax for row m (redundant across the 4 groups, identical)
        float tmax = -INFINITY;
        #pragma unroll
        for (int nn = 0; nn < 32; ++nn) tmax = fmaxf(tmax, s_lds[m][nn]);
        float newmx = fmaxf(mx, tmax);
        float scale = expf(mx - newmx);      // 0 on first tile (mx = -inf)
        float p[32];
        float psum = 0.f;
        #pragma unroll
        for (int nn = 0; nn < 32; ++nn) {
            p[nn] = expf(s_lds[m][nn] - newmx);
            psum += p[nn];
        }
        l = l * scale + psum;
        mx = newmx;
        #pragma unroll
        for (int j = 0; j < 64; ++j) acc[j] *= scale;

        // PV: acc[j] += p[nn] * V'[nn][g*64 + j]
        for (int nn = 0; nn < 32; ++nn) {
            const float4* vrow = (const float4*)&v_lds[nn][g*64];
            float pn = p[nn];
            #pragma unroll
            for (int j4 = 0; j4 < 16; ++j4) {
                float4 v4 = vrow[j4];
                acc[j4*4+0] += pn * v4.x;
                acc[j4*4+1] += pn * v4.y;
                acc[j4*4+2] += pn * v4.z;
                acc[j4*4+3] += pn * v4.w;
            }
        }
        __syncthreads();
    }

    // epilogue: y[b, e, m0+m] = gamma * acc/l + x
    float inv = 1.f / l;
    float gamma = gamma_p[0];
    const size_t base = ((size_t)b*NC + g*64) * NN + m0 + m;
    #pragma unroll
    for (int j = 0; j < 64; ++j) {
        size_t idx = base + (size_t)j * NN;
        y[idx] = gamma * (acc[j] * inv) + x[idx];
    }
}

// ---------------------------------------------------------------------------
extern "C" void kernel_launch(void* const* d_in, const int* in_sizes, int n_in,
                              void* d_out, int out_size, void* d_ws, size_t ws_size,
                              hipStream_t stream) {
    const float* x     = (const float*)d_in[0];
    const float* Wq    = (const float*)d_in[1];
    const float* Wk    = (const float*)d_in[2];
    const float* Wv    = (const float*)d_in[3];
    const float* gamma = (const float*)d_in[4];
    float* y = (float*)d_out;

    float* Pq = (float*)d_ws;                         // [B][N][D] q-proj (keys)
    float* Pk = Pq + (size_t)NB * NN * ND;            // [B][N][D] k-proj (queries)
    float* Vt = Pk + (size_t)NB * NN * ND;            // [B][N][C] v-proj transposed
    // total scratch: 16*4096*(32+32+256)*4 = 83.9 MB

    proj_kernel<<<NB * (NN/32), 256, 0, stream>>>(x, Wq, Wk, Wv, Pq, Pk, Vt);
    attn_kernel<<<NB * (NN/64), 256, 0, stream>>>(Pq, Pk, Vt, x, gamma, y);
}

// Round 2
// 885.642 us; speedup vs baseline: 6.4910x; 6.4910x over previous
//
#include <hip/hip_runtime.h>
#include <math.h>

#define NB 16
#define NC 256
#define NN 4096
#define ND 32

typedef __bf16 bf16_t;
typedef __bf16 bf16x4 __attribute__((ext_vector_type(4)));
typedef __bf16 bf16x8 __attribute__((ext_vector_type(8)));
typedef float  f32x4  __attribute__((ext_vector_type(4)));

// ---------------------------------------------------------------------------
// Kernel 1: fused q/k/v 1x1-conv projections -> bf16 outputs.
//   Pqb[b][n][d] = sum_c Wq[d,c] x[b,c,n]   (keys  K', row-major [n][32])
//   Pkb[b][n][d] = sum_c Wk[d,c] x[b,c,n]   (queries Q', row-major [n][32])
//   Vn [b][e][n] = sum_c Wv[e,c] x[b,c,n]   (V in natural [e][n] layout)
// ---------------------------------------------------------------------------
__global__ __launch_bounds__(256) void proj_kernel(
    const float* __restrict__ x, const float* __restrict__ Wq,
    const float* __restrict__ Wk, const float* __restrict__ Wv,
    bf16_t* __restrict__ Pqb, bf16_t* __restrict__ Pkb, bf16_t* __restrict__ Vn)
{
    __shared__ float xs[NC][33];
    const int b  = blockIdx.x >> 7;
    const int n0 = (blockIdx.x & 127) << 5;
    const int tid = threadIdx.x;
    const float* xb = x + (size_t)b * NC * NN;

    for (int i = tid; i < NC * 32; i += 256) {
        int c = i >> 5, n = i & 31;
        xs[c][n] = xb[(size_t)c * NN + n0 + n];
    }
    __syncthreads();

    const int n = tid & 31;
    const int g = tid >> 5;                    // 0..7

    // q/k: this thread computes d = g*4 + j
    float aq[4] = {0.f,0.f,0.f,0.f}, ak[4] = {0.f,0.f,0.f,0.f};
    for (int c = 0; c < NC; ++c) {
        float xv = xs[c][n];
        #pragma unroll
        for (int j = 0; j < 4; ++j) {
            aq[j] += Wq[(g*4+j)*NC + c] * xv;
            ak[j] += Wk[(g*4+j)*NC + c] * xv;
        }
    }
    {
        size_t row = ((size_t)b * NN + n0 + n) * ND + g*4;
        bf16x4 q4, k4;
        #pragma unroll
        for (int j = 0; j < 4; ++j) { q4[j] = (bf16_t)aq[j]; k4[j] = (bf16_t)ak[j]; }
        *(bf16x4*)(Pqb + row) = q4;
        *(bf16x4*)(Pkb + row) = k4;
    }

    // v: this thread computes e = g*32 + j at column n0+n
    float av[32];
    #pragma unroll
    for (int j = 0; j < 32; ++j) av[j] = 0.f;
    const float4* Wv4 = (const float4*)Wv;
    for (int c4 = 0; c4 < NC/4; ++c4) {
        float x0 = xs[c4*4+0][n], x1 = xs[c4*4+1][n];
        float x2 = xs[c4*4+2][n], x3 = xs[c4*4+3][n];
        #pragma unroll
        for (int j = 0; j < 32; ++j) {
            float4 w = Wv4[(size_t)(g*32+j)*(NC/4) + c4];
            av[j] += w.x*x0 + w.y*x1 + w.z*x2 + w.w*x3;
        }
    }
    #pragma unroll
    for (int j = 0; j < 32; ++j)
        Vn[((size_t)b*NC + g*32 + j)*NN + n0 + n] = (bf16_t)av[j];
}

// ---------------------------------------------------------------------------
// Kernel 2: MFMA flash attention.
//   S[m][n] = Pkb[m,:]·Pqb[n,:]   softmax over n (online, tiles of 64)
//   O^T[e][m] = sum_n V[e][n] P[m][n]   (C rows = e, cols = m -> coalesced y)
// Block: (b, 64-row m-tile), 4 waves; wave w: S rows w*16..w*16+15, O e-strip
// w*64..w*64+63. K and V operands read straight from global (L2-resident);
// only P goes through LDS (XOR-swizzled, double-buffered).
// ---------------------------------------------------------------------------
__global__ __launch_bounds__(256, 2) void attn_mfma(
    const bf16_t* __restrict__ Pqb,   // keys  [B][N][32]
    const bf16_t* __restrict__ Pkb,   // queries [B][N][32]
    const bf16_t* __restrict__ Vn,    // V [B][C][N]
    const float* __restrict__ x,
    const float* __restrict__ gamma_p,
    float* __restrict__ y)
{
    __shared__ bf16_t Plds[2][64*64];     // row stride 128 B, XOR-swizzled
    __shared__ float  scale_lds[2][64];
    __shared__ float  sum_lds[64];

    // XCD-aware swizzle: 1024 blocks, 8 XCDs -> 128 consecutive per XCD
    const int wg  = blockIdx.x;
    const int swb = (wg & 7) * 128 + (wg >> 3);
    const int b   = swb >> 6;
    const int m0  = (swb & 63) << 6;

    const int tid  = threadIdx.x;
    const int lane = tid & 63;
    const int w    = tid >> 6;
    const int lhi  = lane >> 4;      // 0..3
    const int llo  = lane & 15;      // 0..15

    // Q A-frag (hoisted): row = m0 + w*16 + llo, k-bytes = lhi*16
    const bf16x8 qa = *(const bf16x8*)(Pkb + ((size_t)(b*NN + m0 + w*16 + llo)) * ND + lhi*8);

    const bf16_t* Kbase = Pqb + (size_t)b * NN * ND;
    const bf16_t* Vbase = Vn  + ((size_t)b * NC + w*64) * NN;   // wave's e-strip

    f32x4 acc[4][4];                  // [etile][mtile]
    #pragma unroll
    for (int et = 0; et < 4; ++et)
        #pragma unroll
        for (int mt = 0; mt < 4; ++mt)
            acc[et][mt] = (f32x4){0.f,0.f,0.f,0.f};

    float mx[4], sm[4];
    #pragma unroll
    for (int r = 0; r < 4; ++r) { mx[r] = -INFINITY; sm[r] = 0.f; }

    for (int t = 0; t < NN/64; ++t) {
        const int n0  = t * 64;
        const int buf = t & 1;

        // ---- V A-frags for this tile (issued early; used in PV)
        bf16x8 va[4][2];
        #pragma unroll
        for (int et = 0; et < 4; ++et)
            #pragma unroll
            for (int ks = 0; ks < 2; ++ks)
                va[et][ks] = *(const bf16x8*)(Vbase + (size_t)(et*16 + llo) * NN
                                              + n0 + ks*32 + lhi*8);

        // ---- QK^T: S strip [16 m][64 n]
        f32x4 s[4];
        #pragma unroll
        for (int nt = 0; nt < 4; ++nt) {
            bf16x8 kb = *(const bf16x8*)(Kbase + (size_t)(n0 + nt*16 + llo) * ND + lhi*8);
            s[nt] = __builtin_amdgcn_mfma_f32_16x16x32_bf16(qa, kb,
                        (f32x4){0.f,0.f,0.f,0.f}, 0, 0, 0);
        }

        // ---- online softmax (rows m = w*16 + lhi*4 + r)
        float tmax[4], sc[4];
        #pragma unroll
        for (int r = 0; r < 4; ++r) {
            float v = fmaxf(fmaxf(s[0][r], s[1][r]), fmaxf(s[2][r], s[3][r]));
            #pragma unroll
            for (int mask = 1; mask < 16; mask <<= 1)
                v = fmaxf(v, __shfl_xor(v, mask, 64));
            tmax[r] = v;
        }
        #pragma unroll
        for (int r = 0; r < 4; ++r) {
            if (tmax[r] - mx[r] > 8.f) {      // defer-max (T13)
                sc[r] = __expf(mx[r] - tmax[r]);   // first tile: exp(-inf)=0
                mx[r] = tmax[r];
            } else {
                sc[r] = 1.f;
            }
        }
        if (llo == 0) {
            #pragma unroll
            for (int r = 0; r < 4; ++r)
                scale_lds[buf][w*16 + lhi*4 + r] = sc[r];
        }

        float psum[4] = {0.f,0.f,0.f,0.f};
        bf16_t pb[4][4];                   // [nt][r]
        #pragma unroll
        for (int nt = 0; nt < 4; ++nt)
            #pragma unroll
            for (int r = 0; r < 4; ++r) {
                float p = __expf(s[nt][r] - mx[r]);
                psum[r] += p;
                pb[nt][r] = (bf16_t)p;
            }
        #pragma unroll
        for (int r = 0; r < 4; ++r) {
            float v = psum[r];
            #pragma unroll
            for (int mask = 1; mask < 16; mask <<= 1)
                v += __shfl_xor(v, mask, 64);
            sm[r] = sm[r] * sc[r] + v;
        }

        // ---- write P strip to LDS (bf16, XOR-swizzled rows)
        #pragma unroll
        for (int r = 0; r < 4; ++r) {
            const int mloc = w*16 + lhi*4 + r;
            char* rowp = (char*)&Plds[buf][0] + mloc*128;
            const int swz = (mloc & 7) << 4;
            #pragma unroll
            for (int nt = 0; nt < 4; ++nt)
                *(bf16_t*)(rowp + (((nt*16 + llo)*2) ^ swz)) = pb[nt][r];
        }

        __syncthreads();

        // ---- rescale acc (skip when no row rescaled: T13)
        float rs[4];
        #pragma unroll
        for (int mt = 0; mt < 4; ++mt) rs[mt] = scale_lds[buf][mt*16 + llo];
        bool need = (rs[0]!=1.f) | (rs[1]!=1.f) | (rs[2]!=1.f) | (rs[3]!=1.f);
        if (__any(need)) {
            #pragma unroll
            for (int et = 0; et < 4; ++et)
                #pragma unroll
                for (int mt = 0; mt < 4; ++mt)
                    #pragma unroll
                    for (int r = 0; r < 4; ++r)
                        acc[et][mt][r] *= rs[mt];
        }

        // ---- PV: acc[et][mt] += V[et][ks] x P^T[ks][mt]
        #pragma unroll
        for (int ks = 0; ks < 2; ++ks) {
            bf16x8 pfrag[4];
            #pragma unroll
            for (int mt = 0; mt < 4; ++mt) {
                const int row = mt*16 + llo;
                pfrag[mt] = *(const bf16x8*)((char*)&Plds[buf][0] + row*128
                                + ((ks*64 + lhi*16) ^ ((row & 7) << 4)));
            }
            #pragma unroll
            for (int et = 0; et < 4; ++et)
                #pragma unroll
                for (int mt = 0; mt < 4; ++mt)
                    acc[et][mt] = __builtin_amdgcn_mfma_f32_16x16x32_bf16(
                                      va[et][ks], pfrag[mt], acc[et][mt], 0, 0, 0);
        }
        // one barrier per tile is enough: next iter writes buf^1, and writes
        // to this buf can only happen after two more barriers.
    }

    // ---- final denominators
    if (llo == 0) {
        #pragma unroll
        for (int r = 0; r < 4; ++r)
            sum_lds[w*16 + lhi*4 + r] = sm[r];
    }
    __syncthreads();

    const float gamma = gamma_p[0];
    float inv[4];
    #pragma unroll
    for (int mt = 0; mt < 4; ++mt) inv[mt] = 1.f / sum_lds[mt*16 + llo];

    #pragma unroll
    for (int et = 0; et < 4; ++et)
        #pragma unroll
        for (int mt = 0; mt < 4; ++mt) {
            const int m = m0 + mt*16 + llo;
            #pragma unroll
            for (int r = 0; r < 4; ++r) {
                const int e = w*64 + et*16 + lhi*4 + r;
                size_t idx = ((size_t)(b*NC + e)) * NN + m;
                y[idx] = gamma * (acc[et][mt][r] * inv[mt]) + x[idx];
            }
        }
}

// ---------------------------------------------------------------------------
extern "C" void kernel_launch(void* const* d_in, const int* in_sizes, int n_in,
                              void* d_out, int out_size, void* d_ws, size_t ws_size,
                              hipStream_t stream) {
    const float* x     = (const float*)d_in[0];
    const float* Wq    = (const float*)d_in[1];
    const float* Wk    = (const float*)d_in[2];
    const float* Wv    = (const float*)d_in[3];
    const float* gamma = (const float*)d_in[4];
    float* y = (float*)d_out;

    bf16_t* Pqb = (bf16_t*)d_ws;                        // [B][N][32] keys
    bf16_t* Pkb = Pqb + (size_t)NB * NN * ND;           // [B][N][32] queries
    bf16_t* Vnb = Pkb + (size_t)NB * NN * ND;           // [B][C][N]  values
    // scratch: 16*4096*(32+32)*2 + 16*256*4096*2 = 40 MB

    proj_kernel<<<NB * (NN/32), 256, 0, stream>>>(x, Wq, Wk, Wv, Pqb, Pkb, Vnb);
    attn_mfma<<<NB * (NN/64), 256, 0, stream>>>(Pqb, Pkb, Vnb, x, gamma, y);
}

// Round 3
// 354.219 us; speedup vs baseline: 16.2292x; 2.5003x over previous
//
#include <hip/hip_runtime.h>
#include <math.h>

#define NB 16
#define NC 256
#define NN 4096
#define ND 32

typedef __bf16 bf16_t;
typedef __bf16 bf16x4 __attribute__((ext_vector_type(4)));
typedef __bf16 bf16x8 __attribute__((ext_vector_type(8)));
typedef float  f32x4  __attribute__((ext_vector_type(4)));

// ---------------------------------------------------------------------------
// Kernel 0: convert weights to bf16 (+ lo residuals for q/k rows).
// Wb rows: [0,256) = Wv (e), [256,288) = Wq (d), [288,320) = Wk (d).
// Wlo rows: [0,32) = Wq residual, [32,64) = Wk residual.
// ---------------------------------------------------------------------------
__global__ __launch_bounds__(256) void wconv(
    const float* __restrict__ Wq, const float* __restrict__ Wk,
    const float* __restrict__ Wv, bf16_t* __restrict__ Wb, bf16_t* __restrict__ Wlo)
{
    int i = blockIdx.x * 256 + threadIdx.x;
    if (i >= 320 * 256) return;
    int row = i >> 8, c = i & 255;
    float v;
    if (row < 256)      v = Wv[(row      ) * 256 + c];
    else if (row < 288) v = Wq[(row - 256) * 256 + c];
    else                v = Wk[(row - 288) * 256 + c];
    bf16_t h = (bf16_t)v;
    Wb[i] = h;
    if (row >= 256) Wlo[(row - 256) * 256 + c] = (bf16_t)(v - (float)h);
}

// ---------------------------------------------------------------------------
// Kernel 1: fused q/k/v projection as one MFMA GEMM.
//   D[row][n] = sum_c Wb[row][c] * x[b][c][n]   (rows 256..319 with hi/lo split)
// Block: (b, 128-col n-tile), 8 waves = 4 m-strips(80 rows) x 2 n-halves(64).
// x tile staged fp32 in LDS; B-frags assembled with inline bf16 conversion.
// ---------------------------------------------------------------------------
#define BN_P  128
#define KSTEP 64
#define XPAD  130   // fp32 row stride: 8B-aligned, lhi-group bank offset 16

__global__ __launch_bounds__(512) void proj_mfma(
    const float* __restrict__ x, const bf16_t* __restrict__ Wb,
    const bf16_t* __restrict__ Wlo,
    bf16_t* __restrict__ Pqb, bf16_t* __restrict__ Pkb, bf16_t* __restrict__ Vn)
{
    __shared__ float xt[KSTEP][XPAD];   // 33.3 KB

    const int b  = blockIdx.x >> 5;
    const int n0 = (blockIdx.x & 31) * BN_P;
    const int tid  = threadIdx.x;
    const int lane = tid & 63;
    const int w    = tid >> 6;
    const int mstrip = w >> 1;          // 0..3
    const int nh     = w & 1;           // 0..1
    const int llo = lane & 15, lhi = lane >> 4;
    const bool qkwave = (mstrip == 3);  // strip rows 240..319 (mf>=1 are q/k)

    const float* xb = x + (size_t)b * NC * NN + n0;

    f32x4 acc[5][4];
    #pragma unroll
    for (int mf = 0; mf < 5; ++mf)
        #pragma unroll
        for (int nf = 0; nf < 4; ++nf)
            acc[mf][nf] = (f32x4){0.f,0.f,0.f,0.f};

    for (int k0 = 0; k0 < NC; k0 += KSTEP) {
        // ---- stage x[k0:k0+64][n0:n0+128] fp32 -> LDS (coalesced float4)
        #pragma unroll
        for (int p = 0; p < 4; ++p) {
            int idx = p * 512 + tid;          // 0..2047
            int c   = idx >> 5;               // 0..63
            int nn  = (idx & 31) << 2;        // 0..124
            float4 v = *(const float4*)(xb + (size_t)(k0 + c) * NN + nn);
            // two b64 writes (row stride 520 B keeps reads 2-way max)
            *(float2*)&xt[c][nn]     = make_float2(v.x, v.y);
            *(float2*)&xt[c][nn + 2] = make_float2(v.z, v.w);
        }
        __syncthreads();

        #pragma unroll
        for (int ks = 0; ks < 2; ++ks) {
            // A-frags from global (L2-resident weights)
            bf16x8 Ah[5], Al[4];
            #pragma unroll
            for (int mf = 0; mf < 5; ++mf) {
                int row = mstrip * 80 + mf * 16 + llo;
                Ah[mf] = *(const bf16x8*)(Wb + (size_t)row * NC + k0 + ks * 32 + lhi * 8);
            }
            if (qkwave) {
                #pragma unroll
                for (int mf = 1; mf < 5; ++mf) {
                    int row = mstrip * 80 + mf * 16 + llo;   // >= 256
                    Al[mf-1] = *(const bf16x8*)(Wlo + (size_t)(row - 256) * NC
                                                + k0 + ks * 32 + lhi * 8);
                }
            }

            #pragma unroll
            for (int nf = 0; nf < 4; ++nf) {
                const int n  = nh * 64 + nf * 16 + llo;
                const int cb = ks * 32 + lhi * 8;
                bf16x8 bh, bl;
                #pragma unroll
                for (int j = 0; j < 8; ++j) {
                    float f = xt[cb + j][n];
                    bf16_t h = (bf16_t)f;
                    bh[j] = h;
                    if (qkwave) bl[j] = (bf16_t)(f - (float)h);
                }
                #pragma unroll
                for (int mf = 0; mf < 5; ++mf)
                    acc[mf][nf] = __builtin_amdgcn_mfma_f32_16x16x32_bf16(
                                      Ah[mf], bh, acc[mf][nf], 0, 0, 0);
                if (qkwave) {
                    #pragma unroll
                    for (int mf = 1; mf < 5; ++mf) {
                        acc[mf][nf] = __builtin_amdgcn_mfma_f32_16x16x32_bf16(
                                          Al[mf-1], bh, acc[mf][nf], 0, 0, 0);
                        acc[mf][nf] = __builtin_amdgcn_mfma_f32_16x16x32_bf16(
                                          Ah[mf], bl, acc[mf][nf], 0, 0, 0);
                    }
                }
            }
        }
        __syncthreads();
    }

    // ---- epilogue: rows<256 -> Vn[b][e][n]; rows>=256 -> Pqb/Pkb[b][n][d]
    #pragma unroll
    for (int mf = 0; mf < 5; ++mf) {
        const int rowbase = mstrip * 80 + mf * 16 + lhi * 4;
        #pragma unroll
        for (int nf = 0; nf < 4; ++nf) {
            const int n = n0 + nh * 64 + nf * 16 + llo;
            if (rowbase < 256) {
                #pragma unroll
                for (int r = 0; r < 4; ++r)
                    Vn[((size_t)b * NC + rowbase + r) * NN + n] = (bf16_t)acc[mf][nf][r];
            } else {
                const int d = rowbase - 256;      // 0..60, lane has d..d+3
                bf16x4 q4;
                #pragma unroll
                for (int r = 0; r < 4; ++r) q4[r] = (bf16_t)acc[mf][nf][r];
                if (d < 32) *(bf16x4*)(Pqb + ((size_t)b * NN + n) * ND + d) = q4;
                else        *(bf16x4*)(Pkb + ((size_t)b * NN + n) * ND + d - 32) = q4;
            }
        }
    }
}

// ---------------------------------------------------------------------------
// Kernel 2: MFMA flash attention (unchanged from round 2 — passing).
// ---------------------------------------------------------------------------
__global__ __launch_bounds__(256, 2) void attn_mfma(
    const bf16_t* __restrict__ Pqb,   // keys  [B][N][32]
    const bf16_t* __restrict__ Pkb,   // queries [B][N][32]
    const bf16_t* __restrict__ Vn,    // V [B][C][N]
    const float* __restrict__ x,
    const float* __restrict__ gamma_p,
    float* __restrict__ y)
{
    __shared__ bf16_t Plds[2][64*64];
    __shared__ float  scale_lds[2][64];
    __shared__ float  sum_lds[64];

    const int wg  = blockIdx.x;
    const int swb = (wg & 7) * 128 + (wg >> 3);
    const int b   = swb >> 6;
    const int m0  = (swb & 63) << 6;

    const int tid  = threadIdx.x;
    const int lane = tid & 63;
    const int w    = tid >> 6;
    const int lhi  = lane >> 4;
    const int llo  = lane & 15;

    const bf16x8 qa = *(const bf16x8*)(Pkb + ((size_t)(b*NN + m0 + w*16 + llo)) * ND + lhi*8);

    const bf16_t* Kbase = Pqb + (size_t)b * NN * ND;
    const bf16_t* Vbase = Vn  + ((size_t)b * NC + w*64) * NN;

    f32x4 acc[4][4];
    #pragma unroll
    for (int et = 0; et < 4; ++et)
        #pragma unroll
        for (int mt = 0; mt < 4; ++mt)
            acc[et][mt] = (f32x4){0.f,0.f,0.f,0.f};

    float mx[4], sm[4];
    #pragma unroll
    for (int r = 0; r < 4; ++r) { mx[r] = -INFINITY; sm[r] = 0.f; }

    for (int t = 0; t < NN/64; ++t) {
        const int n0  = t * 64;
        const int buf = t & 1;

        bf16x8 va[4][2];
        #pragma unroll
        for (int et = 0; et < 4; ++et)
            #pragma unroll
            for (int ks = 0; ks < 2; ++ks)
                va[et][ks] = *(const bf16x8*)(Vbase + (size_t)(et*16 + llo) * NN
                                              + n0 + ks*32 + lhi*8);

        f32x4 s[4];
        #pragma unroll
        for (int nt = 0; nt < 4; ++nt) {
            bf16x8 kb = *(const bf16x8*)(Kbase + (size_t)(n0 + nt*16 + llo) * ND + lhi*8);
            s[nt] = __builtin_amdgcn_mfma_f32_16x16x32_bf16(qa, kb,
                        (f32x4){0.f,0.f,0.f,0.f}, 0, 0, 0);
        }

        float tmax[4], sc[4];
        #pragma unroll
        for (int r = 0; r < 4; ++r) {
            float v = fmaxf(fmaxf(s[0][r], s[1][r]), fmaxf(s[2][r], s[3][r]));
            #pragma unroll
            for (int mask = 1; mask < 16; mask <<= 1)
                v = fmaxf(v, __shfl_xor(v, mask, 64));
            tmax[r] = v;
        }
        #pragma unroll
        for (int r = 0; r < 4; ++r) {
            if (tmax[r] - mx[r] > 8.f) {
                sc[r] = __expf(mx[r] - tmax[r]);
                mx[r] = tmax[r];
            } else {
                sc[r] = 1.f;
            }
        }
        if (llo == 0) {
            #pragma unroll
            for (int r = 0; r < 4; ++r)
                scale_lds[buf][w*16 + lhi*4 + r] = sc[r];
        }

        float psum[4] = {0.f,0.f,0.f,0.f};
        bf16_t pb[4][4];
        #pragma unroll
        for (int nt = 0; nt < 4; ++nt)
            #pragma unroll
            for (int r = 0; r < 4; ++r) {
                float p = __expf(s[nt][r] - mx[r]);
                psum[r] += p;
                pb[nt][r] = (bf16_t)p;
            }
        #pragma unroll
        for (int r = 0; r < 4; ++r) {
            float v = psum[r];
            #pragma unroll
            for (int mask = 1; mask < 16; mask <<= 1)
                v += __shfl_xor(v, mask, 64);
            sm[r] = sm[r] * sc[r] + v;
        }

        #pragma unroll
        for (int r = 0; r < 4; ++r) {
            const int mloc = w*16 + lhi*4 + r;
            char* rowp = (char*)&Plds[buf][0] + mloc*128;
            const int swz = (mloc & 7) << 4;
            #pragma unroll
            for (int nt = 0; nt < 4; ++nt)
                *(bf16_t*)(rowp + (((nt*16 + llo)*2) ^ swz)) = pb[nt][r];
        }

        __syncthreads();

        float rs[4];
        #pragma unroll
        for (int mt = 0; mt < 4; ++mt) rs[mt] = scale_lds[buf][mt*16 + llo];
        bool need = (rs[0]!=1.f) | (rs[1]!=1.f) | (rs[2]!=1.f) | (rs[3]!=1.f);
        if (__any(need)) {
            #pragma unroll
            for (int et = 0; et < 4; ++et)
                #pragma unroll
                for (int mt = 0; mt < 4; ++mt)
                    #pragma unroll
                    for (int r = 0; r < 4; ++r)
                        acc[et][mt][r] *= rs[mt];
        }

        #pragma unroll
        for (int ks = 0; ks < 2; ++ks) {
            bf16x8 pfrag[4];
            #pragma unroll
            for (int mt = 0; mt < 4; ++mt) {
                const int row = mt*16 + llo;
                pfrag[mt] = *(const bf16x8*)((char*)&Plds[buf][0] + row*128
                                + ((ks*64 + lhi*16) ^ ((row & 7) << 4)));
            }
            #pragma unroll
            for (int et = 0; et < 4; ++et)
                #pragma unroll
                for (int mt = 0; mt < 4; ++mt)
                    acc[et][mt] = __builtin_amdgcn_mfma_f32_16x16x32_bf16(
                                      va[et][ks], pfrag[mt], acc[et][mt], 0, 0, 0);
        }
    }

    if (llo == 0) {
        #pragma unroll
        for (int r = 0; r < 4; ++r)
            sum_lds[w*16 + lhi*4 + r] = sm[r];
    }
    __syncthreads();

    const float gamma = gamma_p[0];
    float inv[4];
    #pragma unroll
    for (int mt = 0; mt < 4; ++mt) inv[mt] = 1.f / sum_lds[mt*16 + llo];

    #pragma unroll
    for (int et = 0; et < 4; ++et)
        #pragma unroll
        for (int mt = 0; mt < 4; ++mt) {
            const int m = m0 + mt*16 + llo;
            #pragma unroll
            for (int r = 0; r < 4; ++r) {
                const int e = w*64 + et*16 + lhi*4 + r;
                size_t idx = ((size_t)(b*NC + e)) * NN + m;
                y[idx] = gamma * (acc[et][mt][r] * inv[mt]) + x[idx];
            }
        }
}

// ---------------------------------------------------------------------------
extern "C" void kernel_launch(void* const* d_in, const int* in_sizes, int n_in,
                              void* d_out, int out_size, void* d_ws, size_t ws_size,
                              hipStream_t stream) {
    const float* x     = (const float*)d_in[0];
    const float* Wq    = (const float*)d_in[1];
    const float* Wk    = (const float*)d_in[2];
    const float* Wv    = (const float*)d_in[3];
    const float* gamma = (const float*)d_in[4];
    float* y = (float*)d_out;

    bf16_t* Pqb = (bf16_t*)d_ws;
    bf16_t* Pkb = Pqb + (size_t)NB * NN * ND;
    bf16_t* Vnb = Pkb + (size_t)NB * NN * ND;
    bf16_t* Wb  = Vnb + (size_t)NB * NC * NN;
    bf16_t* Wlo = Wb  + 320 * 256;
    // scratch: 8.4 + 33.6 + 0.2 MB ~= 42 MB

    wconv<<<320, 256, 0, stream>>>(Wq, Wk, Wv, Wb, Wlo);
    proj_mfma<<<NB * (NN / BN_P), 512, 0, stream>>>(x, Wb, Wlo, Pqb, Pkb, Vnb);
    attn_mfma<<<NB * (NN/64), 256, 0, stream>>>(Pqb, Pkb, Vnb, x, gamma, y);
}